// Round 5
// baseline (44706.577 us; speedup 1.0000x reference)
//
#include <hip/hip_runtime.h>
#include <hip/hip_bf16.h>
#include <math.h>

#define NP 16384
#define CI 512
#define CO 512
#define NE 262144
#define MS 8192
#define BN_EPS 1e-5f
#define NCELL 4096

// ---------------------------------------------------------------------------
// GEMM: H[n][o] = sum_k X[n][k]*W[o][k] + b[o]
// ---------------------------------------------------------------------------
__global__ __launch_bounds__(256) void gemm_kernel(const float* __restrict__ X,
                                                   const float* __restrict__ W,
                                                   const float* __restrict__ bias,
                                                   float* __restrict__ H) {
  __shared__ float As[16][65];
  __shared__ float Bs[16][65];
  const int bm = blockIdx.x * 64;
  const int bn = blockIdx.y * 64;
  const int t  = threadIdx.x;
  const int tm = (t >> 4) << 2;
  const int tn = (t & 15) << 2;
  const int lr = t >> 2;
  const int lc = (t & 3) << 2;

  float acc[4][4] = {};

  for (int k0 = 0; k0 < CI; k0 += 16) {
    float4 a = *(const float4*)(X + (size_t)(bm + lr) * CI + k0 + lc);
    float4 b = *(const float4*)(W + (size_t)(bn + lr) * CI + k0 + lc);
    As[lc + 0][lr] = a.x; As[lc + 1][lr] = a.y; As[lc + 2][lr] = a.z; As[lc + 3][lr] = a.w;
    Bs[lc + 0][lr] = b.x; Bs[lc + 1][lr] = b.y; Bs[lc + 2][lr] = b.z; Bs[lc + 3][lr] = b.w;
    __syncthreads();
#pragma unroll
    for (int k = 0; k < 16; ++k) {
      float av[4], bv[4];
#pragma unroll
      for (int i = 0; i < 4; ++i) av[i] = As[k][tm + i];
#pragma unroll
      for (int j = 0; j < 4; ++j) bv[j] = Bs[k][tn + j];
#pragma unroll
      for (int i = 0; i < 4; ++i)
#pragma unroll
        for (int j = 0; j < 4; ++j) acc[i][j] += av[i] * bv[j];
    }
    __syncthreads();
  }
#pragma unroll
  for (int i = 0; i < 4; ++i)
#pragma unroll
    for (int j = 0; j < 4; ++j)
      H[(size_t)(bm + tm + i) * CO + bn + tn + j] = acc[i][j] + bias[bn + tn + j];
}

// ---------------------------------------------------------------------------
// BN
// ---------------------------------------------------------------------------
__global__ __launch_bounds__(256) void bn_stats_kernel(const float* __restrict__ H,
                                                       float* __restrict__ psum,
                                                       float* __restrict__ psq) {
  const int col = blockIdx.x * 256 + threadIdx.x;
  const int r0  = blockIdx.y * 256;
  float s = 0.f, q = 0.f;
  for (int r = r0; r < r0 + 256; ++r) {
    float v = H[(size_t)r * CO + col];
    s += v;
    q += v * v;
  }
  psum[blockIdx.y * CO + col] = s;
  psq [blockIdx.y * CO + col] = q;
}

__global__ __launch_bounds__(512) void bn_final_kernel(const float* __restrict__ psum,
                                                       const float* __restrict__ psq,
                                                       const float* __restrict__ gamma,
                                                       const float* __restrict__ beta,
                                                       float* __restrict__ scale,
                                                       float* __restrict__ shift) {
  const int c = threadIdx.x;
  float s = 0.f, q = 0.f;
  for (int r = 0; r < 64; ++r) {
    s += psum[r * CO + c];
    q += psq [r * CO + c];
  }
  const float inv_n = 1.0f / (float)NP;
  float mu  = s * inv_n;
  float var = q * inv_n - mu * mu;
  float rs  = rsqrtf(var + BN_EPS);
  float a   = rs * gamma[c];
  scale[c] = a;
  shift[c] = beta[c] - mu * a;
}

__global__ __launch_bounds__(256) void bn_relu_kernel(float* __restrict__ H,
                                                      const float* __restrict__ scale,
                                                      const float* __restrict__ shift) {
  __shared__ float sc[CO], sh[CO];
  for (int i = threadIdx.x; i < CO; i += 256) { sc[i] = scale[i]; sh[i] = shift[i]; }
  __syncthreads();
  const int total4 = NP * CO / 4;
  const int stride = gridDim.x * blockDim.x;
  for (int idx = blockIdx.x * blockDim.x + threadIdx.x; idx < total4; idx += stride) {
    float4 v = ((float4*)H)[idx];
    int c = (idx << 2) & (CO - 1);
    v.x = fmaxf(fmaf(v.x, sc[c + 0], sh[c + 0]), 0.f);
    v.y = fmaxf(fmaf(v.y, sc[c + 1], sh[c + 1]), 0.f);
    v.z = fmaxf(fmaf(v.z, sc[c + 2], sh[c + 2]), 0.f);
    v.w = fmaxf(fmaf(v.w, sc[c + 3], sh[c + 3]), 0.f);
    ((float4*)H)[idx] = v;
  }
}

// ---------------------------------------------------------------------------
// Morton-cell counting sort
// ---------------------------------------------------------------------------
__device__ __forceinline__ unsigned p3(unsigned v) {
  v &= 0x3FFu;
  v = (v * 0x00010001u) & 0xFF0000FFu;
  v = (v * 0x00000101u) & 0x0F00F00Fu;
  v = (v * 0x00000011u) & 0xC30C30C3u;
  v = (v * 0x00000005u) & 0x49249249u;
  return v;
}

__global__ __launch_bounds__(256) void cell_kernel(const float* __restrict__ pos,
                                                   int* __restrict__ cid,
                                                   int* __restrict__ cnt) {
  int i = blockIdx.x * 256 + threadIdx.x;
  if (i < NP) {
    int cx = min(15, max(0, (int)(pos[3 * i + 0] * 16.f)));
    int cy = min(15, max(0, (int)(pos[3 * i + 1] * 16.f)));
    int cz = min(15, max(0, (int)(pos[3 * i + 2] * 16.f)));
    int c = (int)(p3(cx) | (p3(cy) << 1) | (p3(cz) << 2));
    cid[i] = c;
    atomicAdd(&cnt[c], 1);
  }
}

__global__ __launch_bounds__(1024) void cellscan_kernel(const int* __restrict__ cnt,
                                                        int* __restrict__ ccur) {
  const int t = threadIdx.x;
  const int base = t * 4;
  int c[4];
  int s = 0;
#pragma unroll
  for (int j = 0; j < 4; ++j) { c[j] = cnt[base + j]; s += c[j]; }
  const int lane = t & 63, wid = t >> 6;
  int incl = s;
#pragma unroll
  for (int off = 1; off < 64; off <<= 1) {
    int v = __shfl_up(incl, off);
    if (lane >= off) incl += v;
  }
  __shared__ int wtot[16];
  if (lane == 63) wtot[wid] = incl;
  __syncthreads();
  if (t < 16) {
    int v = wtot[t];
    int p = v;
#pragma unroll
    for (int off = 1; off < 16; off <<= 1) {
      int u = __shfl_up(p, off);
      if (t >= off) p += u;
    }
    wtot[t] = p - v;
  }
  __syncthreads();
  int off = wtot[wid] + incl - s;
#pragma unroll
  for (int j = 0; j < 4; ++j) { ccur[base + j] = off; off += c[j]; }
}

__global__ __launch_bounds__(256) void cellscatter_kernel(const float* __restrict__ pos,
                                                          const int* __restrict__ cid,
                                                          int* __restrict__ ccur,
                                                          float4* __restrict__ spos) {
  int i = blockIdx.x * 256 + threadIdx.x;
  if (i < NP) {
    int p = atomicAdd(&ccur[cid[i]], 1);
    spos[p] = make_float4(pos[3 * i + 0], pos[3 * i + 1], pos[3 * i + 2],
                          __int_as_float(i));
  }
}

// ---------------------------------------------------------------------------
// FPS: 4 waves (256 threads), 64 register-resident points/thread,
// 4 subgroups x 16 pts with center+radius pruning, DPP wave argmax,
// one barrier/iteration via double-buffered 4-slot LDS exchange.
// dmin update keeps the exact XLA rounding chain; fmin is exact, so
// skipping provably-no-op centers is bit-safe (margins ~1e-4 >> fp error).
// ---------------------------------------------------------------------------
template <int CTRL>
__device__ __forceinline__ float dpp_max_step(float v) {
  int o = __builtin_amdgcn_update_dpp(__float_as_int(v), __float_as_int(v),
                                      CTRL, 0xf, 0xf, false);
  return fmaxf(v, __int_as_float(o));
}
__device__ __forceinline__ float readlane_f(float v, int lane) {
  return __int_as_float(__builtin_amdgcn_readlane(__float_as_int(v), lane));
}

__global__ __launch_bounds__(256, 1) void fps_kernel(const float4* __restrict__ spos,
                                                     const float* __restrict__ pos,
                                                     int* __restrict__ flags) {
  const int t = threadIdx.x;
  const int lane = t & 63;
  const int w = t >> 6;

  __shared__ int    sorig[NP];     // sorted -> original index (64 KB)
  __shared__ float4 slotv[2][4];
  __shared__ float  slotz[2][4];

  float px[64], py[64], pz[64], dmin[64];
  const float4* sp = spos + (size_t)t * 64;
#pragma unroll
  for (int k = 0; k < 64; ++k) {
    float4 p = sp[k];
    px[k] = p.x; py[k] = p.y; pz[k] = p.z;
    dmin[k] = __builtin_huge_valf();
    sorig[t * 64 + k] = __float_as_int(p.w);
  }

  // subgroup geometry: center + inflated radius
  float cgx[4], cgy[4], cgz[4], rg[4], ssq[4];
  float sval[4], sx_[4], sy_[4], sz_[4];
  int   sidx[4];
#pragma unroll
  for (int g = 0; g < 4; ++g) {
    float lox = px[g * 16], hix = lox, loy = py[g * 16], hiy = loy;
    float loz = pz[g * 16], hiz = loz;
#pragma unroll
    for (int j = 1; j < 16; ++j) {
      const int k = g * 16 + j;
      lox = fminf(lox, px[k]); hix = fmaxf(hix, px[k]);
      loy = fminf(loy, py[k]); hiy = fmaxf(hiy, py[k]);
      loz = fminf(loz, pz[k]); hiz = fmaxf(hiz, pz[k]);
    }
    float cx = 0.5f * (lox + hix), cy = 0.5f * (loy + hiy), cz = 0.5f * (loz + hiz);
    float r2 = 0.f;
#pragma unroll
    for (int j = 0; j < 16; ++j) {
      const int k = g * 16 + j;
      float dx = px[k] - cx, dy = py[k] - cy, dz = pz[k] - cz;
      r2 = fmaxf(r2, dx * dx + dy * dy + dz * dz);
    }
    cgx[g] = cx; cgy[g] = cy; cgz[g] = cz;
    rg[g]  = sqrtf(r2) * 1.0001f + 1e-7f;
    ssq[g] = __builtin_huge_valf();
    sval[g] = -1.f; sidx[g] = g * 16; sx_[g] = cx; sy_[g] = cy; sz_[g] = cz;
  }

  float ccx = pos[0], ccy = pos[1], ccz = pos[2];
  if (t == 0) flags[0] = 1;
  __syncthreads();

  for (int it = 1; it < MS; ++it) {
#pragma unroll
    for (int g = 0; g < 4; ++g) {
      float dxc = ccx - cgx[g], dyc = ccy - cgy[g], dzc = ccz - cgz[g];
      float d2c = fmaf(dxc, dxc, fmaf(dyc, dyc, dzc * dzc));
      float thr = ssq[g] + rg[g];
      if (d2c < thr * thr) {   // subgroup may change: recompute (wave skips if none)
        float bv = -1.f, bx = 0.f, by = 0.f, bz = 0.f;
        int bi = 0;
#pragma unroll
        for (int j = 0; j < 16; ++j) {
          const int k = g * 16 + j;
          float dx = __fsub_rn(px[k], ccx);
          float dy = __fsub_rn(py[k], ccy);
          float dz = __fsub_rn(pz[k], ccz);
          float d  = __fadd_rn(__fadd_rn(__fmul_rn(dx, dx), __fmul_rn(dy, dy)),
                               __fmul_rn(dz, dz));
          float dm = fminf(dmin[k], d);
          dmin[k] = dm;
          if (dm > bv) { bv = dm; bi = k; bx = px[k]; by = py[k]; bz = pz[k]; }
        }
        sval[g] = bv; sidx[g] = bi; sx_[g] = bx; sy_[g] = by; sz_[g] = bz;
        ssq[g]  = sqrtf(bv) * 1.0001f;
      }
    }
    // lane reduce over 4 subgroup records (ascending g keeps lowest index on tie)
    float v = sval[0]; int ki = sidx[0];
    float x = sx_[0], y = sy_[0], z = sz_[0];
#pragma unroll
    for (int g = 1; g < 4; ++g) {
      if (sval[g] > v) { v = sval[g]; ki = sidx[g]; x = sx_[g]; y = sy_[g]; z = sz_[g]; }
    }
    int gi = t * 64 + ki;

    // wave argmax: DPP value max -> lane 63, then ballot + readlane extraction
    float m = v;
    m = dpp_max_step<0x111>(m);  // row_shr:1
    m = dpp_max_step<0x112>(m);  // row_shr:2
    m = dpp_max_step<0x114>(m);  // row_shr:4
    m = dpp_max_step<0x118>(m);  // row_shr:8
    m = dpp_max_step<0x142>(m);  // row_bcast:15
    m = dpp_max_step<0x143>(m);  // row_bcast:31
    float wmax = readlane_f(m, 63);
    unsigned long long ball = __ballot(v == wmax);
    int srcl = (int)__ffsll(ball) - 1;          // lowest lane = lowest sorted idx
    int   widx = __builtin_amdgcn_readlane(gi, srcl);
    float wx = readlane_f(x, srcl);
    float wy = readlane_f(y, srcl);
    float wz = readlane_f(z, srcl);

    const int b = it & 1;
    if (lane == 0) {
      slotv[b][w] = make_float4(wmax, __int_as_float(widx), wx, wy);
      slotz[b][w] = wz;
    }
    __syncthreads();

    float gv = -1.f; int gidx = 0; float nx = 0.f, ny = 0.f, nz = 0.f;
#pragma unroll
    for (int q = 0; q < 4; ++q) {
      float4 s = slotv[b][q];
      float  sz2 = slotz[b][q];
      int si = __float_as_int(s.y);
      if (s.x > gv || (s.x == gv && si < gidx)) {
        gv = s.x; gidx = si; nx = s.z; ny = s.w; nz = sz2;
      }
    }
    ccx = nx; ccy = ny; ccz = nz;
    if (t == 0) flags[sorig[gidx]] = 1;
  }
}

// ---------------------------------------------------------------------------
// Compact flags -> sorted selected original indices
// ---------------------------------------------------------------------------
__global__ __launch_bounds__(1024) void compact_kernel(const int* __restrict__ flags,
                                                       int* __restrict__ sel) {
  const int t = threadIdx.x;
  const int base = t * 16;
  int f[16];
  int cnt = 0;
#pragma unroll
  for (int j = 0; j < 16; ++j) { f[j] = flags[base + j]; cnt += f[j]; }
  const int lane = t & 63, wid = t >> 6;
  int incl = cnt;
#pragma unroll
  for (int off = 1; off < 64; off <<= 1) {
    int v = __shfl_up(incl, off);
    if (lane >= off) incl += v;
  }
  __shared__ int wtot[16];
  if (lane == 63) wtot[wid] = incl;
  __syncthreads();
  if (t < 16) {
    int v = wtot[t];
    int s = v;
#pragma unroll
    for (int off = 1; off < 16; off <<= 1) {
      int u = __shfl_up(s, off);
      if (t >= off) s += u;
    }
    wtot[t] = s - v;
  }
  __syncthreads();
  int off = wtot[wid] + incl - cnt;
#pragma unroll
  for (int j = 0; j < 16; ++j)
    if (f[j]) sel[off++] = base + j;
}

// ---------------------------------------------------------------------------
// Edge CSR by dst
// ---------------------------------------------------------------------------
__global__ __launch_bounds__(256) void edge_count_kernel(const int* __restrict__ edge,
                                                         int* __restrict__ count) {
  const int stride = gridDim.x * blockDim.x;
  for (int e = blockIdx.x * blockDim.x + threadIdx.x; e < NE; e += stride)
    atomicAdd(&count[edge[NE + e]], 1);
}

__global__ __launch_bounds__(1024) void scan_offsets_kernel(const int* __restrict__ count,
                                                            int* __restrict__ offs,
                                                            int* __restrict__ cursor) {
  const int t = threadIdx.x;
  const int base = t * 16;
  int c[16];
  int cnt = 0;
#pragma unroll
  for (int j = 0; j < 16; ++j) { c[j] = count[base + j]; cnt += c[j]; }
  const int lane = t & 63, wid = t >> 6;
  int incl = cnt;
#pragma unroll
  for (int off = 1; off < 64; off <<= 1) {
    int v = __shfl_up(incl, off);
    if (lane >= off) incl += v;
  }
  __shared__ int wtot[16];
  if (lane == 63) wtot[wid] = incl;
  __syncthreads();
  if (t < 16) {
    int v = wtot[t];
    int s = v;
#pragma unroll
    for (int off = 1; off < 16; off <<= 1) {
      int u = __shfl_up(s, off);
      if (t >= off) s += u;
    }
    wtot[t] = s - v;
  }
  __syncthreads();
  int off = wtot[wid] + incl - cnt;
#pragma unroll
  for (int j = 0; j < 16; ++j) {
    offs[base + j] = off;
    cursor[base + j] = off;
    off += c[j];
  }
  if (t == 1023) offs[NP] = off;
}

__global__ __launch_bounds__(256) void edge_scatter_kernel(const int* __restrict__ edge,
                                                           int* __restrict__ cursor,
                                                           int* __restrict__ esrc) {
  const int stride = gridDim.x * blockDim.x;
  for (int e = blockIdx.x * blockDim.x + threadIdx.x; e < NE; e += stride) {
    int p = atomicAdd(&cursor[edge[NE + e]], 1);
    esrc[p] = edge[e];
  }
}

// ---------------------------------------------------------------------------
// Pool + gather
// ---------------------------------------------------------------------------
__global__ __launch_bounds__(256) void pool_kernel(const float* __restrict__ H,
                                                   const int* __restrict__ sel,
                                                   const int* __restrict__ offs,
                                                   const int* __restrict__ esrc,
                                                   float* __restrict__ out) {
  const int m = blockIdx.x;
  const int i = sel[m];
  const int c = threadIdx.x;
  float v0 = H[(size_t)i * CO + c];
  float v1 = H[(size_t)i * CO + c + 256];
  const int s0 = offs[i], s1 = offs[i + 1];
  for (int k = s0; k < s1; ++k) {
    const int s = esrc[k];
    v0 = fmaxf(v0, H[(size_t)s * CO + c]);
    v1 = fmaxf(v1, H[(size_t)s * CO + c + 256]);
  }
  out[(size_t)m * CO + c] = v0;
  out[(size_t)m * CO + c + 256] = v1;
}

__global__ __launch_bounds__(256) void gather_pb_kernel(const float* __restrict__ pos,
                                                        const int* __restrict__ batch,
                                                        const int* __restrict__ sel,
                                                        float* __restrict__ out) {
  const int m = blockIdx.x * blockDim.x + threadIdx.x;
  if (m < MS) {
    const int i = sel[m];
    float* opos = out + (size_t)MS * CO;
    opos[3 * m + 0] = pos[3 * i + 0];
    opos[3 * m + 1] = pos[3 * i + 1];
    opos[3 * m + 2] = pos[3 * i + 2];
    ((int*)out)[(size_t)MS * CO + MS * 3 + m] = batch[i];
  }
}

// ---------------------------------------------------------------------------
extern "C" void kernel_launch(void* const* d_in, const int* in_sizes, int n_in,
                              void* d_out, int out_size, void* d_ws, size_t ws_size,
                              hipStream_t stream) {
  const float* x     = (const float*)d_in[0];
  const float* pos   = (const float*)d_in[1];
  const int*   batch = (const int*)  d_in[2];
  const int*   edge  = (const int*)  d_in[3];
  const float* W     = (const float*)d_in[4];
  const float* bias  = (const float*)d_in[5];
  const float* gamma = (const float*)d_in[6];
  const float* beta  = (const float*)d_in[7];
  float* out = (float*)d_out;

  char* ws = (char*)d_ws;
  size_t off = 0;
  auto alloc = [&](size_t bytes) -> void* {
    void* p = ws + off;
    off += (bytes + 255) & ~(size_t)255;
    return p;
  };
  float*  H      = (float*)alloc((size_t)NP * CO * 4);
  float*  psum   = (float*)alloc(64 * CO * 4);
  float*  psq    = (float*)alloc(64 * CO * 4);
  float*  scale  = (float*)alloc(CO * 4);
  float*  shift  = (float*)alloc(CO * 4);
  int*    flags  = (int*)  alloc(NP * 4);
  int*    sel    = (int*)  alloc(MS * 4);
  int*    count  = (int*)  alloc(NP * 4);
  int*    offs   = (int*)  alloc((NP + 1) * 4);
  int*    cursor = (int*)  alloc(NP * 4);
  int*    esrc   = (int*)  alloc(NE * 4);
  int*    cid    = (int*)  alloc(NP * 4);
  int*    cnt    = (int*)  alloc(NCELL * 4);
  int*    ccur   = (int*)  alloc(NCELL * 4);
  float4* spos   = (float4*)alloc((size_t)NP * 16);
  (void)ws_size;

  hipMemsetAsync(flags, 0, NP * 4, stream);
  hipMemsetAsync(count, 0, NP * 4, stream);
  hipMemsetAsync(cnt,   0, NCELL * 4, stream);

  // spatial sort for FPS pruning
  cell_kernel<<<NP / 256, 256, 0, stream>>>(pos, cid, cnt);
  cellscan_kernel<<<1, 1024, 0, stream>>>(cnt, ccur);
  cellscatter_kernel<<<NP / 256, 256, 0, stream>>>(pos, cid, ccur, spos);
  // FPS
  fps_kernel<<<1, 256, 0, stream>>>(spos, pos, flags);
  compact_kernel<<<1, 1024, 0, stream>>>(flags, sel);
  // Linear + BN + ReLU
  gemm_kernel<<<dim3(NP / 64, CO / 64), 256, 0, stream>>>(x, W, bias, H);
  bn_stats_kernel<<<dim3(2, 64), 256, 0, stream>>>(H, psum, psq);
  bn_final_kernel<<<1, 512, 0, stream>>>(psum, psq, gamma, beta, scale, shift);
  bn_relu_kernel<<<2048, 256, 0, stream>>>(H, scale, shift);
  // edge CSR by dst
  edge_count_kernel<<<512, 256, 0, stream>>>(edge, count);
  scan_offsets_kernel<<<1, 1024, 0, stream>>>(count, offs, cursor);
  edge_scatter_kernel<<<512, 256, 0, stream>>>(edge, cursor, esrc);
  // pooled features + pos/batch gather
  pool_kernel<<<MS, 256, 0, stream>>>(H, sel, offs, esrc, out);
  gather_pb_kernel<<<MS / 256, 256, 0, stream>>>(pos, batch, sel, out);
}

// Round 6
// 18303.458 us; speedup vs baseline: 2.4425x; 2.4425x over previous
//
#include <hip/hip_runtime.h>
#include <hip/hip_bf16.h>
#include <math.h>

#define NP 16384
#define CI 512
#define CO 512
#define NE 262144
#define MS 8192
#define BN_EPS 1e-5f
#define NCELL 4096

// ---------------------------------------------------------------------------
// GEMM: H[n][o] = sum_k X[n][k]*W[o][k] + b[o]
// ---------------------------------------------------------------------------
__global__ __launch_bounds__(256) void gemm_kernel(const float* __restrict__ X,
                                                   const float* __restrict__ W,
                                                   const float* __restrict__ bias,
                                                   float* __restrict__ H) {
  __shared__ float As[16][65];
  __shared__ float Bs[16][65];
  const int bm = blockIdx.x * 64;
  const int bn = blockIdx.y * 64;
  const int t  = threadIdx.x;
  const int tm = (t >> 4) << 2;
  const int tn = (t & 15) << 2;
  const int lr = t >> 2;
  const int lc = (t & 3) << 2;

  float acc[4][4] = {};

  for (int k0 = 0; k0 < CI; k0 += 16) {
    float4 a = *(const float4*)(X + (size_t)(bm + lr) * CI + k0 + lc);
    float4 b = *(const float4*)(W + (size_t)(bn + lr) * CI + k0 + lc);
    As[lc + 0][lr] = a.x; As[lc + 1][lr] = a.y; As[lc + 2][lr] = a.z; As[lc + 3][lr] = a.w;
    Bs[lc + 0][lr] = b.x; Bs[lc + 1][lr] = b.y; Bs[lc + 2][lr] = b.z; Bs[lc + 3][lr] = b.w;
    __syncthreads();
#pragma unroll
    for (int k = 0; k < 16; ++k) {
      float av[4], bv[4];
#pragma unroll
      for (int i = 0; i < 4; ++i) av[i] = As[k][tm + i];
#pragma unroll
      for (int j = 0; j < 4; ++j) bv[j] = Bs[k][tn + j];
#pragma unroll
      for (int i = 0; i < 4; ++i)
#pragma unroll
        for (int j = 0; j < 4; ++j) acc[i][j] += av[i] * bv[j];
    }
    __syncthreads();
  }
#pragma unroll
  for (int i = 0; i < 4; ++i)
#pragma unroll
    for (int j = 0; j < 4; ++j)
      H[(size_t)(bm + tm + i) * CO + bn + tn + j] = acc[i][j] + bias[bn + tn + j];
}

// ---------------------------------------------------------------------------
// BN
// ---------------------------------------------------------------------------
__global__ __launch_bounds__(256) void bn_stats_kernel(const float* __restrict__ H,
                                                       float* __restrict__ psum,
                                                       float* __restrict__ psq) {
  const int col = blockIdx.x * 256 + threadIdx.x;
  const int r0  = blockIdx.y * 256;
  float s = 0.f, q = 0.f;
  for (int r = r0; r < r0 + 256; ++r) {
    float v = H[(size_t)r * CO + col];
    s += v;
    q += v * v;
  }
  psum[blockIdx.y * CO + col] = s;
  psq [blockIdx.y * CO + col] = q;
}

__global__ __launch_bounds__(512) void bn_final_kernel(const float* __restrict__ psum,
                                                       const float* __restrict__ psq,
                                                       const float* __restrict__ gamma,
                                                       const float* __restrict__ beta,
                                                       float* __restrict__ scale,
                                                       float* __restrict__ shift) {
  const int c = threadIdx.x;
  float s = 0.f, q = 0.f;
  for (int r = 0; r < 64; ++r) {
    s += psum[r * CO + c];
    q += psq [r * CO + c];
  }
  const float inv_n = 1.0f / (float)NP;
  float mu  = s * inv_n;
  float var = q * inv_n - mu * mu;
  float rs  = rsqrtf(var + BN_EPS);
  float a   = rs * gamma[c];
  scale[c] = a;
  shift[c] = beta[c] - mu * a;
}

__global__ __launch_bounds__(256) void bn_relu_kernel(float* __restrict__ H,
                                                      const float* __restrict__ scale,
                                                      const float* __restrict__ shift) {
  __shared__ float sc[CO], sh[CO];
  for (int i = threadIdx.x; i < CO; i += 256) { sc[i] = scale[i]; sh[i] = shift[i]; }
  __syncthreads();
  const int total4 = NP * CO / 4;
  const int stride = gridDim.x * blockDim.x;
  for (int idx = blockIdx.x * blockDim.x + threadIdx.x; idx < total4; idx += stride) {
    float4 v = ((float4*)H)[idx];
    int c = (idx << 2) & (CO - 1);
    v.x = fmaxf(fmaf(v.x, sc[c + 0], sh[c + 0]), 0.f);
    v.y = fmaxf(fmaf(v.y, sc[c + 1], sh[c + 1]), 0.f);
    v.z = fmaxf(fmaf(v.z, sc[c + 2], sh[c + 2]), 0.f);
    v.w = fmaxf(fmaf(v.w, sc[c + 3], sh[c + 3]), 0.f);
    ((float4*)H)[idx] = v;
  }
}

// ---------------------------------------------------------------------------
// Morton-cell counting sort
// ---------------------------------------------------------------------------
__device__ __forceinline__ unsigned p3(unsigned v) {
  v &= 0x3FFu;
  v = (v * 0x00010001u) & 0xFF0000FFu;
  v = (v * 0x00000101u) & 0x0F00F00Fu;
  v = (v * 0x00000011u) & 0xC30C30C3u;
  v = (v * 0x00000005u) & 0x49249249u;
  return v;
}

__global__ __launch_bounds__(256) void cell_kernel(const float* __restrict__ pos,
                                                   int* __restrict__ cid,
                                                   int* __restrict__ cnt) {
  int i = blockIdx.x * 256 + threadIdx.x;
  if (i < NP) {
    int cx = min(15, max(0, (int)(pos[3 * i + 0] * 16.f)));
    int cy = min(15, max(0, (int)(pos[3 * i + 1] * 16.f)));
    int cz = min(15, max(0, (int)(pos[3 * i + 2] * 16.f)));
    int c = (int)(p3(cx) | (p3(cy) << 1) | (p3(cz) << 2));
    cid[i] = c;
    atomicAdd(&cnt[c], 1);
  }
}

__global__ __launch_bounds__(1024) void cellscan_kernel(const int* __restrict__ cnt,
                                                        int* __restrict__ ccur) {
  const int t = threadIdx.x;
  const int base = t * 4;
  int c[4];
  int s = 0;
#pragma unroll
  for (int j = 0; j < 4; ++j) { c[j] = cnt[base + j]; s += c[j]; }
  const int lane = t & 63, wid = t >> 6;
  int incl = s;
#pragma unroll
  for (int off = 1; off < 64; off <<= 1) {
    int v = __shfl_up(incl, off);
    if (lane >= off) incl += v;
  }
  __shared__ int wtot[16];
  if (lane == 63) wtot[wid] = incl;
  __syncthreads();
  if (t < 16) {
    int v = wtot[t];
    int p = v;
#pragma unroll
    for (int off = 1; off < 16; off <<= 1) {
      int u = __shfl_up(p, off);
      if (t >= off) p += u;
    }
    wtot[t] = p - v;
  }
  __syncthreads();
  int off = wtot[wid] + incl - s;
#pragma unroll
  for (int j = 0; j < 4; ++j) { ccur[base + j] = off; off += c[j]; }
}

__global__ __launch_bounds__(256) void cellscatter_kernel(const float* __restrict__ pos,
                                                          const int* __restrict__ cid,
                                                          int* __restrict__ ccur,
                                                          float4* __restrict__ spos) {
  int i = blockIdx.x * 256 + threadIdx.x;
  if (i < NP) {
    int p = atomicAdd(&ccur[cid[i]], 1);
    spos[p] = make_float4(pos[3 * i + 0], pos[3 * i + 1], pos[3 * i + 2],
                          __int_as_float(i));
  }
}

// ---------------------------------------------------------------------------
// FPS: 512 threads (8 waves, 2/SIMD -> VGPR budget 256), 32 register-resident
// points/thread (128 VGPR state -> no spill), 2 subgroups x 16 pts with
// center+radius pruning, DPP wave argmax, one barrier/iteration via
// double-buffered 8-slot LDS exchange. dmin update keeps the exact XLA
// rounding chain; fmin is exact, so skipping provably-no-op centers is
// bit-safe (margins ~1e-4 >> fp error).
// ---------------------------------------------------------------------------
template <int CTRL>
__device__ __forceinline__ float dpp_max_step(float v) {
  int o = __builtin_amdgcn_update_dpp(__float_as_int(v), __float_as_int(v),
                                      CTRL, 0xf, 0xf, false);
  return fmaxf(v, __int_as_float(o));
}
__device__ __forceinline__ float readlane_f(float v, int lane) {
  return __int_as_float(__builtin_amdgcn_readlane(__float_as_int(v), lane));
}

__global__ __launch_bounds__(512, 2) void fps_kernel(const float4* __restrict__ spos,
                                                     const float* __restrict__ pos,
                                                     int* __restrict__ flags) {
  const int t = threadIdx.x;
  const int lane = t & 63;
  const int w = t >> 6;      // 0..7

  __shared__ int    sorig[NP];     // sorted -> original index (64 KB)
  __shared__ float4 slotv[2][8];
  __shared__ float  slotz[2][8];

  float px[32], py[32], pz[32], dmin[32];   // 128 VGPRs, static indexing only
  const float4* sp = spos + (size_t)t * 32;
#pragma unroll
  for (int k = 0; k < 32; ++k) {
    float4 p = sp[k];
    px[k] = p.x; py[k] = p.y; pz[k] = p.z;
    dmin[k] = __builtin_huge_valf();
    sorig[t * 32 + k] = __float_as_int(p.w);
  }

  // subgroup geometry: center + inflated radius (2 groups of 16)
  float cgx[2], cgy[2], cgz[2], rg[2], ssq[2];
  float sval[2], sx_[2], sy_[2], sz_[2];
  int   sidx[2];
#pragma unroll
  for (int g = 0; g < 2; ++g) {
    float lox = px[g * 16], hix = lox, loy = py[g * 16], hiy = loy;
    float loz = pz[g * 16], hiz = loz;
#pragma unroll
    for (int j = 1; j < 16; ++j) {
      const int k = g * 16 + j;
      lox = fminf(lox, px[k]); hix = fmaxf(hix, px[k]);
      loy = fminf(loy, py[k]); hiy = fmaxf(hiy, py[k]);
      loz = fminf(loz, pz[k]); hiz = fmaxf(hiz, pz[k]);
    }
    float cx = 0.5f * (lox + hix), cy = 0.5f * (loy + hiy), cz = 0.5f * (loz + hiz);
    float r2 = 0.f;
#pragma unroll
    for (int j = 0; j < 16; ++j) {
      const int k = g * 16 + j;
      float dx = px[k] - cx, dy = py[k] - cy, dz = pz[k] - cz;
      r2 = fmaxf(r2, dx * dx + dy * dy + dz * dz);
    }
    cgx[g] = cx; cgy[g] = cy; cgz[g] = cz;
    rg[g]  = sqrtf(r2) * 1.0001f + 1e-7f;
    ssq[g] = __builtin_huge_valf();
    sval[g] = -1.f; sidx[g] = g * 16; sx_[g] = cx; sy_[g] = cy; sz_[g] = cz;
  }

  float ccx = pos[0], ccy = pos[1], ccz = pos[2];
  if (t == 0) flags[0] = 1;
  __syncthreads();

  for (int it = 1; it < MS; ++it) {
#pragma unroll
    for (int g = 0; g < 2; ++g) {
      float dxc = ccx - cgx[g], dyc = ccy - cgy[g], dzc = ccz - cgz[g];
      float d2c = fmaf(dxc, dxc, fmaf(dyc, dyc, dzc * dzc));
      float thr = ssq[g] + rg[g];
      if (d2c < thr * thr) {   // subgroup may change: recompute (exec-masked)
        float bv = -1.f, bx = 0.f, by = 0.f, bz = 0.f;
        int bi = 0;
#pragma unroll
        for (int j = 0; j < 16; ++j) {
          const int k = g * 16 + j;
          float dx = __fsub_rn(px[k], ccx);
          float dy = __fsub_rn(py[k], ccy);
          float dz = __fsub_rn(pz[k], ccz);
          float d  = __fadd_rn(__fadd_rn(__fmul_rn(dx, dx), __fmul_rn(dy, dy)),
                               __fmul_rn(dz, dz));
          float dm = fminf(dmin[k], d);
          dmin[k] = dm;
          if (dm > bv) { bv = dm; bi = k; bx = px[k]; by = py[k]; bz = pz[k]; }
        }
        sval[g] = bv; sidx[g] = bi; sx_[g] = bx; sy_[g] = by; sz_[g] = bz;
        ssq[g]  = sqrtf(bv) * 1.0001f;
      }
    }
    // lane reduce over 2 subgroup records (ascending g keeps lowest index on tie)
    float v = sval[0]; int ki = sidx[0];
    float x = sx_[0], y = sy_[0], z = sz_[0];
    if (sval[1] > v) { v = sval[1]; ki = sidx[1]; x = sx_[1]; y = sy_[1]; z = sz_[1]; }
    int gi = t * 32 + ki;

    // wave argmax: DPP value max -> lane 63, then ballot + readlane extraction
    float m = v;
    m = dpp_max_step<0x111>(m);  // row_shr:1
    m = dpp_max_step<0x112>(m);  // row_shr:2
    m = dpp_max_step<0x114>(m);  // row_shr:4
    m = dpp_max_step<0x118>(m);  // row_shr:8
    m = dpp_max_step<0x142>(m);  // row_bcast:15
    m = dpp_max_step<0x143>(m);  // row_bcast:31
    float wmax = readlane_f(m, 63);
    unsigned long long ball = __ballot(v == wmax);
    int srcl = (int)__ffsll(ball) - 1;          // lowest lane = lowest sorted idx
    int   widx = __builtin_amdgcn_readlane(gi, srcl);
    float wx = readlane_f(x, srcl);
    float wy = readlane_f(y, srcl);
    float wz = readlane_f(z, srcl);

    const int b = it & 1;
    if (lane == 0) {
      slotv[b][w] = make_float4(wmax, __int_as_float(widx), wx, wy);
      slotz[b][w] = wz;
    }
    __syncthreads();

    float gv = -1.f; int gidx = 0; float nx = 0.f, ny = 0.f, nz = 0.f;
#pragma unroll
    for (int q = 0; q < 8; ++q) {
      float4 s = slotv[b][q];
      float  sz2 = slotz[b][q];
      int si = __float_as_int(s.y);
      if (s.x > gv || (s.x == gv && si < gidx)) {
        gv = s.x; gidx = si; nx = s.z; ny = s.w; nz = sz2;
      }
    }
    ccx = nx; ccy = ny; ccz = nz;
    if (t == 0) flags[sorig[gidx]] = 1;
  }
}

// ---------------------------------------------------------------------------
// Compact flags -> sorted selected original indices
// ---------------------------------------------------------------------------
__global__ __launch_bounds__(1024) void compact_kernel(const int* __restrict__ flags,
                                                       int* __restrict__ sel) {
  const int t = threadIdx.x;
  const int base = t * 16;
  int f[16];
  int cnt = 0;
#pragma unroll
  for (int j = 0; j < 16; ++j) { f[j] = flags[base + j]; cnt += f[j]; }
  const int lane = t & 63, wid = t >> 6;
  int incl = cnt;
#pragma unroll
  for (int off = 1; off < 64; off <<= 1) {
    int v = __shfl_up(incl, off);
    if (lane >= off) incl += v;
  }
  __shared__ int wtot[16];
  if (lane == 63) wtot[wid] = incl;
  __syncthreads();
  if (t < 16) {
    int v = wtot[t];
    int s = v;
#pragma unroll
    for (int off = 1; off < 16; off <<= 1) {
      int u = __shfl_up(s, off);
      if (t >= off) s += u;
    }
    wtot[t] = s - v;
  }
  __syncthreads();
  int off = wtot[wid] + incl - cnt;
#pragma unroll
  for (int j = 0; j < 16; ++j)
    if (f[j]) sel[off++] = base + j;
}

// ---------------------------------------------------------------------------
// Edge CSR by dst
// ---------------------------------------------------------------------------
__global__ __launch_bounds__(256) void edge_count_kernel(const int* __restrict__ edge,
                                                         int* __restrict__ count) {
  const int stride = gridDim.x * blockDim.x;
  for (int e = blockIdx.x * blockDim.x + threadIdx.x; e < NE; e += stride)
    atomicAdd(&count[edge[NE + e]], 1);
}

__global__ __launch_bounds__(1024) void scan_offsets_kernel(const int* __restrict__ count,
                                                            int* __restrict__ offs,
                                                            int* __restrict__ cursor) {
  const int t = threadIdx.x;
  const int base = t * 16;
  int c[16];
  int cnt = 0;
#pragma unroll
  for (int j = 0; j < 16; ++j) { c[j] = count[base + j]; cnt += c[j]; }
  const int lane = t & 63, wid = t >> 6;
  int incl = cnt;
#pragma unroll
  for (int off = 1; off < 64; off <<= 1) {
    int v = __shfl_up(incl, off);
    if (lane >= off) incl += v;
  }
  __shared__ int wtot[16];
  if (lane == 63) wtot[wid] = incl;
  __syncthreads();
  if (t < 16) {
    int v = wtot[t];
    int s = v;
#pragma unroll
    for (int off = 1; off < 16; off <<= 1) {
      int u = __shfl_up(s, off);
      if (t >= off) s += u;
    }
    wtot[t] = s - v;
  }
  __syncthreads();
  int off = wtot[wid] + incl - cnt;
#pragma unroll
  for (int j = 0; j < 16; ++j) {
    offs[base + j] = off;
    cursor[base + j] = off;
    off += c[j];
  }
  if (t == 1023) offs[NP] = off;
}

__global__ __launch_bounds__(256) void edge_scatter_kernel(const int* __restrict__ edge,
                                                           int* __restrict__ cursor,
                                                           int* __restrict__ esrc) {
  const int stride = gridDim.x * blockDim.x;
  for (int e = blockIdx.x * blockDim.x + threadIdx.x; e < NE; e += stride) {
    int p = atomicAdd(&cursor[edge[NE + e]], 1);
    esrc[p] = edge[e];
  }
}

// ---------------------------------------------------------------------------
// Pool + gather
// ---------------------------------------------------------------------------
__global__ __launch_bounds__(256) void pool_kernel(const float* __restrict__ H,
                                                   const int* __restrict__ sel,
                                                   const int* __restrict__ offs,
                                                   const int* __restrict__ esrc,
                                                   float* __restrict__ out) {
  const int m = blockIdx.x;
  const int i = sel[m];
  const int c = threadIdx.x;
  float v0 = H[(size_t)i * CO + c];
  float v1 = H[(size_t)i * CO + c + 256];
  const int s0 = offs[i], s1 = offs[i + 1];
  for (int k = s0; k < s1; ++k) {
    const int s = esrc[k];
    v0 = fmaxf(v0, H[(size_t)s * CO + c]);
    v1 = fmaxf(v1, H[(size_t)s * CO + c + 256]);
  }
  out[(size_t)m * CO + c] = v0;
  out[(size_t)m * CO + c + 256] = v1;
}

__global__ __launch_bounds__(256) void gather_pb_kernel(const float* __restrict__ pos,
                                                        const int* __restrict__ batch,
                                                        const int* __restrict__ sel,
                                                        float* __restrict__ out) {
  const int m = blockIdx.x * blockDim.x + threadIdx.x;
  if (m < MS) {
    const int i = sel[m];
    float* opos = out + (size_t)MS * CO;
    opos[3 * m + 0] = pos[3 * i + 0];
    opos[3 * m + 1] = pos[3 * i + 1];
    opos[3 * m + 2] = pos[3 * i + 2];
    ((int*)out)[(size_t)MS * CO + MS * 3 + m] = batch[i];
  }
}

// ---------------------------------------------------------------------------
extern "C" void kernel_launch(void* const* d_in, const int* in_sizes, int n_in,
                              void* d_out, int out_size, void* d_ws, size_t ws_size,
                              hipStream_t stream) {
  const float* x     = (const float*)d_in[0];
  const float* pos   = (const float*)d_in[1];
  const int*   batch = (const int*)  d_in[2];
  const int*   edge  = (const int*)  d_in[3];
  const float* W     = (const float*)d_in[4];
  const float* bias  = (const float*)d_in[5];
  const float* gamma = (const float*)d_in[6];
  const float* beta  = (const float*)d_in[7];
  float* out = (float*)d_out;

  char* ws = (char*)d_ws;
  size_t off = 0;
  auto alloc = [&](size_t bytes) -> void* {
    void* p = ws + off;
    off += (bytes + 255) & ~(size_t)255;
    return p;
  };
  float*  H      = (float*)alloc((size_t)NP * CO * 4);
  float*  psum   = (float*)alloc(64 * CO * 4);
  float*  psq    = (float*)alloc(64 * CO * 4);
  float*  scale  = (float*)alloc(CO * 4);
  float*  shift  = (float*)alloc(CO * 4);
  int*    flags  = (int*)  alloc(NP * 4);
  int*    sel    = (int*)  alloc(MS * 4);
  int*    count  = (int*)  alloc(NP * 4);
  int*    offs   = (int*)  alloc((NP + 1) * 4);
  int*    cursor = (int*)  alloc(NP * 4);
  int*    esrc   = (int*)  alloc(NE * 4);
  int*    cid    = (int*)  alloc(NP * 4);
  int*    cnt    = (int*)  alloc(NCELL * 4);
  int*    ccur   = (int*)  alloc(NCELL * 4);
  float4* spos   = (float4*)alloc((size_t)NP * 16);
  (void)ws_size;

  hipMemsetAsync(flags, 0, NP * 4, stream);
  hipMemsetAsync(count, 0, NP * 4, stream);
  hipMemsetAsync(cnt,   0, NCELL * 4, stream);

  // spatial sort for FPS pruning
  cell_kernel<<<NP / 256, 256, 0, stream>>>(pos, cid, cnt);
  cellscan_kernel<<<1, 1024, 0, stream>>>(cnt, ccur);
  cellscatter_kernel<<<NP / 256, 256, 0, stream>>>(pos, cid, ccur, spos);
  // FPS
  fps_kernel<<<1, 512, 0, stream>>>(spos, pos, flags);
  compact_kernel<<<1, 1024, 0, stream>>>(flags, sel);
  // Linear + BN + ReLU
  gemm_kernel<<<dim3(NP / 64, CO / 64), 256, 0, stream>>>(x, W, bias, H);
  bn_stats_kernel<<<dim3(2, 64), 256, 0, stream>>>(H, psum, psq);
  bn_final_kernel<<<1, 512, 0, stream>>>(psum, psq, gamma, beta, scale, shift);
  bn_relu_kernel<<<2048, 256, 0, stream>>>(H, scale, shift);
  // edge CSR by dst
  edge_count_kernel<<<512, 256, 0, stream>>>(edge, count);
  scan_offsets_kernel<<<1, 1024, 0, stream>>>(count, offs, cursor);
  edge_scatter_kernel<<<512, 256, 0, stream>>>(edge, cursor, esrc);
  // pooled features + pos/batch gather
  pool_kernel<<<MS, 256, 0, stream>>>(H, sel, offs, esrc, out);
  gather_pb_kernel<<<MS / 256, 256, 0, stream>>>(pos, batch, sel, out);
}

// Round 7
// 13720.822 us; speedup vs baseline: 3.2583x; 1.3340x over previous
//
#include <hip/hip_runtime.h>
#include <hip/hip_bf16.h>
#include <math.h>

#define NP 16384
#define CI 512
#define CO 512
#define NE 262144
#define MS 8192
#define BN_EPS 1e-5f
#define NCELL 4096

// ---------------------------------------------------------------------------
// GEMM: H[n][o] = sum_k X[n][k]*W[o][k] + b[o]
// ---------------------------------------------------------------------------
__global__ __launch_bounds__(256) void gemm_kernel(const float* __restrict__ X,
                                                   const float* __restrict__ W,
                                                   const float* __restrict__ bias,
                                                   float* __restrict__ H) {
  __shared__ float As[16][65];
  __shared__ float Bs[16][65];
  const int bm = blockIdx.x * 64;
  const int bn = blockIdx.y * 64;
  const int t  = threadIdx.x;
  const int tm = (t >> 4) << 2;
  const int tn = (t & 15) << 2;
  const int lr = t >> 2;
  const int lc = (t & 3) << 2;

  float acc[4][4] = {};

  for (int k0 = 0; k0 < CI; k0 += 16) {
    float4 a = *(const float4*)(X + (size_t)(bm + lr) * CI + k0 + lc);
    float4 b = *(const float4*)(W + (size_t)(bn + lr) * CI + k0 + lc);
    As[lc + 0][lr] = a.x; As[lc + 1][lr] = a.y; As[lc + 2][lr] = a.z; As[lc + 3][lr] = a.w;
    Bs[lc + 0][lr] = b.x; Bs[lc + 1][lr] = b.y; Bs[lc + 2][lr] = b.z; Bs[lc + 3][lr] = b.w;
    __syncthreads();
#pragma unroll
    for (int k = 0; k < 16; ++k) {
      float av[4], bv[4];
#pragma unroll
      for (int i = 0; i < 4; ++i) av[i] = As[k][tm + i];
#pragma unroll
      for (int j = 0; j < 4; ++j) bv[j] = Bs[k][tn + j];
#pragma unroll
      for (int i = 0; i < 4; ++i)
#pragma unroll
        for (int j = 0; j < 4; ++j) acc[i][j] += av[i] * bv[j];
    }
    __syncthreads();
  }
#pragma unroll
  for (int i = 0; i < 4; ++i)
#pragma unroll
    for (int j = 0; j < 4; ++j)
      H[(size_t)(bm + tm + i) * CO + bn + tn + j] = acc[i][j] + bias[bn + tn + j];
}

// ---------------------------------------------------------------------------
// BN
// ---------------------------------------------------------------------------
__global__ __launch_bounds__(256) void bn_stats_kernel(const float* __restrict__ H,
                                                       float* __restrict__ psum,
                                                       float* __restrict__ psq) {
  const int col = blockIdx.x * 256 + threadIdx.x;
  const int r0  = blockIdx.y * 256;
  float s = 0.f, q = 0.f;
  for (int r = r0; r < r0 + 256; ++r) {
    float v = H[(size_t)r * CO + col];
    s += v;
    q += v * v;
  }
  psum[blockIdx.y * CO + col] = s;
  psq [blockIdx.y * CO + col] = q;
}

__global__ __launch_bounds__(512) void bn_final_kernel(const float* __restrict__ psum,
                                                       const float* __restrict__ psq,
                                                       const float* __restrict__ gamma,
                                                       const float* __restrict__ beta,
                                                       float* __restrict__ scale,
                                                       float* __restrict__ shift) {
  const int c = threadIdx.x;
  float s = 0.f, q = 0.f;
  for (int r = 0; r < 64; ++r) {
    s += psum[r * CO + c];
    q += psq [r * CO + c];
  }
  const float inv_n = 1.0f / (float)NP;
  float mu  = s * inv_n;
  float var = q * inv_n - mu * mu;
  float rs  = rsqrtf(var + BN_EPS);
  float a   = rs * gamma[c];
  scale[c] = a;
  shift[c] = beta[c] - mu * a;
}

__global__ __launch_bounds__(256) void bn_relu_kernel(float* __restrict__ H,
                                                      const float* __restrict__ scale,
                                                      const float* __restrict__ shift) {
  __shared__ float sc[CO], sh[CO];
  for (int i = threadIdx.x; i < CO; i += 256) { sc[i] = scale[i]; sh[i] = shift[i]; }
  __syncthreads();
  const int total4 = NP * CO / 4;
  const int stride = gridDim.x * blockDim.x;
  for (int idx = blockIdx.x * blockDim.x + threadIdx.x; idx < total4; idx += stride) {
    float4 v = ((float4*)H)[idx];
    int c = (idx << 2) & (CO - 1);
    v.x = fmaxf(fmaf(v.x, sc[c + 0], sh[c + 0]), 0.f);
    v.y = fmaxf(fmaf(v.y, sc[c + 1], sh[c + 1]), 0.f);
    v.z = fmaxf(fmaf(v.z, sc[c + 2], sh[c + 2]), 0.f);
    v.w = fmaxf(fmaf(v.w, sc[c + 3], sh[c + 3]), 0.f);
    ((float4*)H)[idx] = v;
  }
}

// ---------------------------------------------------------------------------
// Morton-cell counting sort
// ---------------------------------------------------------------------------
__device__ __forceinline__ unsigned p3(unsigned v) {
  v &= 0x3FFu;
  v = (v * 0x00010001u) & 0xFF0000FFu;
  v = (v * 0x00000101u) & 0x0F00F00Fu;
  v = (v * 0x00000011u) & 0xC30C30C3u;
  v = (v * 0x00000005u) & 0x49249249u;
  return v;
}

__global__ __launch_bounds__(256) void cell_kernel(const float* __restrict__ pos,
                                                   int* __restrict__ cid,
                                                   int* __restrict__ cnt) {
  int i = blockIdx.x * 256 + threadIdx.x;
  if (i < NP) {
    int cx = min(15, max(0, (int)(pos[3 * i + 0] * 16.f)));
    int cy = min(15, max(0, (int)(pos[3 * i + 1] * 16.f)));
    int cz = min(15, max(0, (int)(pos[3 * i + 2] * 16.f)));
    int c = (int)(p3(cx) | (p3(cy) << 1) | (p3(cz) << 2));
    cid[i] = c;
    atomicAdd(&cnt[c], 1);
  }
}

__global__ __launch_bounds__(1024) void cellscan_kernel(const int* __restrict__ cnt,
                                                        int* __restrict__ ccur) {
  const int t = threadIdx.x;
  const int base = t * 4;
  int c[4];
  int s = 0;
#pragma unroll
  for (int j = 0; j < 4; ++j) { c[j] = cnt[base + j]; s += c[j]; }
  const int lane = t & 63, wid = t >> 6;
  int incl = s;
#pragma unroll
  for (int off = 1; off < 64; off <<= 1) {
    int v = __shfl_up(incl, off);
    if (lane >= off) incl += v;
  }
  __shared__ int wtot[16];
  if (lane == 63) wtot[wid] = incl;
  __syncthreads();
  if (t < 16) {
    int v = wtot[t];
    int p = v;
#pragma unroll
    for (int off = 1; off < 16; off <<= 1) {
      int u = __shfl_up(p, off);
      if (t >= off) p += u;
    }
    wtot[t] = p - v;
  }
  __syncthreads();
  int off = wtot[wid] + incl - s;
#pragma unroll
  for (int j = 0; j < 4; ++j) { ccur[base + j] = off; off += c[j]; }
}

__global__ __launch_bounds__(256) void cellscatter_kernel(const float* __restrict__ pos,
                                                          const int* __restrict__ cid,
                                                          int* __restrict__ ccur,
                                                          float4* __restrict__ spos) {
  int i = blockIdx.x * 256 + threadIdx.x;
  if (i < NP) {
    int p = atomicAdd(&ccur[cid[i]], 1);
    spos[p] = make_float4(pos[3 * i + 0], pos[3 * i + 1], pos[3 * i + 2],
                          __int_as_float(i));
  }
}

// ---------------------------------------------------------------------------
// FPS: 1024 threads (16 waves, 4/SIMD), 16 register-resident points/lane in
// ONE subgroup with center+radius pruning. Idle waves (__any(hit)==0) skip
// the whole argmax block via a wave-uniform branch and replay a cached slot.
// Slim exchange: each lane reads slot (lane&15), 4-step shfl_xor reduce on
// (val,slot), readlane winner coords. One barrier/iteration, double-buffered
// slots. dmin update keeps the exact XLA rounding chain; fmin is exact, so
// skipping provably-no-op centers is bit-safe (margin 1e-4 >> fp error).
// Tie-breaks everywhere resolve to lowest sorted index (first-max).
// ---------------------------------------------------------------------------
template <int CTRL>
__device__ __forceinline__ float dpp_max_step(float v) {
  int o = __builtin_amdgcn_update_dpp(__float_as_int(v), __float_as_int(v),
                                      CTRL, 0xf, 0xf, false);
  return fmaxf(v, __int_as_float(o));
}
__device__ __forceinline__ float readlane_f(float v, int lane) {
  return __int_as_float(__builtin_amdgcn_readlane(__float_as_int(v), lane));
}

__global__ __launch_bounds__(1024, 1) void fps_kernel(const float4* __restrict__ spos,
                                                      const float* __restrict__ pos,
                                                      int* __restrict__ flags) {
  const int t = threadIdx.x;
  const int lane = t & 63;
  const int w = t >> 6;      // 0..15

  __shared__ int    sorig[NP];     // sorted -> original index (64 KB)
  __shared__ float4 slotA[2][16];  // (val, x, y, z)
  __shared__ int    slotB[2][16];  // winner sorted index

  float px[16], py[16], pz[16], dmin[16];
  const float4* sp = spos + (size_t)t * 16;
#pragma unroll
  for (int k = 0; k < 16; ++k) {
    float4 p = sp[k];
    px[k] = p.x; py[k] = p.y; pz[k] = p.z;
    dmin[k] = __builtin_huge_valf();
    sorig[t * 16 + k] = __float_as_int(p.w);
  }

  // subgroup geometry: center + inflated radius (one group of 16)
  float lox = px[0], hix = lox, loy = py[0], hiy = loy, loz = pz[0], hiz = loz;
#pragma unroll
  for (int j = 1; j < 16; ++j) {
    lox = fminf(lox, px[j]); hix = fmaxf(hix, px[j]);
    loy = fminf(loy, py[j]); hiy = fmaxf(hiy, py[j]);
    loz = fminf(loz, pz[j]); hiz = fmaxf(hiz, pz[j]);
  }
  const float cgx = 0.5f * (lox + hix), cgy = 0.5f * (loy + hiy), cgz = 0.5f * (loz + hiz);
  float r2 = 0.f;
#pragma unroll
  for (int j = 0; j < 16; ++j) {
    float dx = px[j] - cgx, dy = py[j] - cgy, dz = pz[j] - cgz;
    r2 = fmaxf(r2, dx * dx + dy * dy + dz * dz);
  }
  const float rad = sqrtf(r2) * 1.0001f + 1e-7f;
  float ssq  = __builtin_huge_valf();  // inflated sqrt of group max dmin
  float sval = -1.f;                   // group max dmin
  float sx = cgx, sy = cgy, sz = cgz;  // group winner coords
  int   sk = 0;                        // group winner k

  // cached wave-winner slot payload (wave-uniform after first iteration)
  float cwv = -1.f, cwx = 0.f, cwy = 0.f, cwz = 0.f;
  int   cwi = 0;

  float ccx = pos[0], ccy = pos[1], ccz = pos[2];
  if (t == 0) flags[0] = 1;
  __syncthreads();

  for (int it = 1; it < MS; ++it) {
    float dxc = ccx - cgx, dyc = ccy - cgy, dzc = ccz - cgz;
    float d2c = fmaf(dxc, dxc, fmaf(dyc, dyc, dzc * dzc));
    float thr = ssq + rad;
    bool hit = d2c < thr * thr;
    if (__any(hit)) {           // wave-uniform: idle waves skip everything
      if (hit) {                // lane-divergent: recompute this lane's group
        float bv = -1.f, bx = 0.f, by = 0.f, bz = 0.f;
        int bk = 0;
#pragma unroll
        for (int k = 0; k < 16; ++k) {
          float dx = __fsub_rn(px[k], ccx);
          float dy = __fsub_rn(py[k], ccy);
          float dz = __fsub_rn(pz[k], ccz);
          float d  = __fadd_rn(__fadd_rn(__fmul_rn(dx, dx), __fmul_rn(dy, dy)),
                               __fmul_rn(dz, dz));
          float dm = fminf(dmin[k], d);
          dmin[k] = dm;
          if (dm > bv) { bv = dm; bk = k; bx = px[k]; by = py[k]; bz = pz[k]; }
        }
        sval = bv; sk = bk; sx = bx; sy = by; sz = bz;
        ssq  = sqrtf(bv) * 1.0001f;
      }
      // wave argmax: DPP value max -> lane 63, ballot + readlane extraction
      float v = sval;
      float m = v;
      m = dpp_max_step<0x111>(m);  // row_shr:1
      m = dpp_max_step<0x112>(m);  // row_shr:2
      m = dpp_max_step<0x114>(m);  // row_shr:4
      m = dpp_max_step<0x118>(m);  // row_shr:8
      m = dpp_max_step<0x142>(m);  // row_bcast:15
      m = dpp_max_step<0x143>(m);  // row_bcast:31
      float wmax = readlane_f(m, 63);
      unsigned long long ball = __ballot(v == wmax);
      int srcl = (int)__ffsll(ball) - 1;   // lowest lane = lowest sorted idx
      int gi = t * 16 + sk;
      cwi = __builtin_amdgcn_readlane(gi, srcl);
      cwx = readlane_f(sx, srcl);
      cwy = readlane_f(sy, srcl);
      cwz = readlane_f(sz, srcl);
      cwv = wmax;
    }
    const int b = it & 1;
    if (lane == 0) {
      slotA[b][w] = make_float4(cwv, cwx, cwy, cwz);
      slotB[b][w] = cwi;
    }
    __syncthreads();

    // exchange: lane reads slot (lane&15); 4-step shfl_xor reduce on (v,slot)
    const int q = lane & 15;
    float4 sa = slotA[b][q];
    int    sb = slotB[b][q];
    float v2 = sa.x;
    int   qi = q;
#pragma unroll
    for (int off = 1; off < 16; off <<= 1) {
      float ov = __shfl_xor(v2, off);
      int   oq = __shfl_xor(qi, off);
      if (ov > v2 || (ov == v2 && oq < qi)) { v2 = ov; qi = oq; }
    }
    // winner slot qi is uniform; its payload lives in lane qi (qi < 16)
    ccx = readlane_f(sa.y, qi);
    ccy = readlane_f(sa.z, qi);
    ccz = readlane_f(sa.w, qi);
    if (t == 0) {
      int gidx = __builtin_amdgcn_readlane(sb, qi);
      flags[sorig[gidx]] = 1;
    }
  }
}

// ---------------------------------------------------------------------------
// Compact flags -> sorted selected original indices
// ---------------------------------------------------------------------------
__global__ __launch_bounds__(1024) void compact_kernel(const int* __restrict__ flags,
                                                       int* __restrict__ sel) {
  const int t = threadIdx.x;
  const int base = t * 16;
  int f[16];
  int cnt = 0;
#pragma unroll
  for (int j = 0; j < 16; ++j) { f[j] = flags[base + j]; cnt += f[j]; }
  const int lane = t & 63, wid = t >> 6;
  int incl = cnt;
#pragma unroll
  for (int off = 1; off < 64; off <<= 1) {
    int v = __shfl_up(incl, off);
    if (lane >= off) incl += v;
  }
  __shared__ int wtot[16];
  if (lane == 63) wtot[wid] = incl;
  __syncthreads();
  if (t < 16) {
    int v = wtot[t];
    int s = v;
#pragma unroll
    for (int off = 1; off < 16; off <<= 1) {
      int u = __shfl_up(s, off);
      if (t >= off) s += u;
    }
    wtot[t] = s - v;
  }
  __syncthreads();
  int off = wtot[wid] + incl - cnt;
#pragma unroll
  for (int j = 0; j < 16; ++j)
    if (f[j]) sel[off++] = base + j;
}

// ---------------------------------------------------------------------------
// Edge CSR by dst
// ---------------------------------------------------------------------------
__global__ __launch_bounds__(256) void edge_count_kernel(const int* __restrict__ edge,
                                                         int* __restrict__ count) {
  const int stride = gridDim.x * blockDim.x;
  for (int e = blockIdx.x * blockDim.x + threadIdx.x; e < NE; e += stride)
    atomicAdd(&count[edge[NE + e]], 1);
}

__global__ __launch_bounds__(1024) void scan_offsets_kernel(const int* __restrict__ count,
                                                            int* __restrict__ offs,
                                                            int* __restrict__ cursor) {
  const int t = threadIdx.x;
  const int base = t * 16;
  int c[16];
  int cnt = 0;
#pragma unroll
  for (int j = 0; j < 16; ++j) { c[j] = count[base + j]; cnt += c[j]; }
  const int lane = t & 63, wid = t >> 6;
  int incl = cnt;
#pragma unroll
  for (int off = 1; off < 64; off <<= 1) {
    int v = __shfl_up(incl, off);
    if (lane >= off) incl += v;
  }
  __shared__ int wtot[16];
  if (lane == 63) wtot[wid] = incl;
  __syncthreads();
  if (t < 16) {
    int v = wtot[t];
    int s = v;
#pragma unroll
    for (int off = 1; off < 16; off <<= 1) {
      int u = __shfl_up(s, off);
      if (t >= off) s += u;
    }
    wtot[t] = s - v;
  }
  __syncthreads();
  int off = wtot[wid] + incl - cnt;
#pragma unroll
  for (int j = 0; j < 16; ++j) {
    offs[base + j] = off;
    cursor[base + j] = off;
    off += c[j];
  }
  if (t == 1023) offs[NP] = off;
}

__global__ __launch_bounds__(256) void edge_scatter_kernel(const int* __restrict__ edge,
                                                           int* __restrict__ cursor,
                                                           int* __restrict__ esrc) {
  const int stride = gridDim.x * blockDim.x;
  for (int e = blockIdx.x * blockDim.x + threadIdx.x; e < NE; e += stride) {
    int p = atomicAdd(&cursor[edge[NE + e]], 1);
    esrc[p] = edge[e];
  }
}

// ---------------------------------------------------------------------------
// Pool + gather
// ---------------------------------------------------------------------------
__global__ __launch_bounds__(256) void pool_kernel(const float* __restrict__ H,
                                                   const int* __restrict__ sel,
                                                   const int* __restrict__ offs,
                                                   const int* __restrict__ esrc,
                                                   float* __restrict__ out) {
  const int m = blockIdx.x;
  const int i = sel[m];
  const int c = threadIdx.x;
  float v0 = H[(size_t)i * CO + c];
  float v1 = H[(size_t)i * CO + c + 256];
  const int s0 = offs[i], s1 = offs[i + 1];
  for (int k = s0; k < s1; ++k) {
    const int s = esrc[k];
    v0 = fmaxf(v0, H[(size_t)s * CO + c]);
    v1 = fmaxf(v1, H[(size_t)s * CO + c + 256]);
  }
  out[(size_t)m * CO + c] = v0;
  out[(size_t)m * CO + c + 256] = v1;
}

__global__ __launch_bounds__(256) void gather_pb_kernel(const float* __restrict__ pos,
                                                        const int* __restrict__ batch,
                                                        const int* __restrict__ sel,
                                                        float* __restrict__ out) {
  const int m = blockIdx.x * blockDim.x + threadIdx.x;
  if (m < MS) {
    const int i = sel[m];
    float* opos = out + (size_t)MS * CO;
    opos[3 * m + 0] = pos[3 * i + 0];
    opos[3 * m + 1] = pos[3 * i + 1];
    opos[3 * m + 2] = pos[3 * i + 2];
    ((int*)out)[(size_t)MS * CO + MS * 3 + m] = batch[i];
  }
}

// ---------------------------------------------------------------------------
extern "C" void kernel_launch(void* const* d_in, const int* in_sizes, int n_in,
                              void* d_out, int out_size, void* d_ws, size_t ws_size,
                              hipStream_t stream) {
  const float* x     = (const float*)d_in[0];
  const float* pos   = (const float*)d_in[1];
  const int*   batch = (const int*)  d_in[2];
  const int*   edge  = (const int*)  d_in[3];
  const float* W     = (const float*)d_in[4];
  const float* bias  = (const float*)d_in[5];
  const float* gamma = (const float*)d_in[6];
  const float* beta  = (const float*)d_in[7];
  float* out = (float*)d_out;

  char* ws = (char*)d_ws;
  size_t off = 0;
  auto alloc = [&](size_t bytes) -> void* {
    void* p = ws + off;
    off += (bytes + 255) & ~(size_t)255;
    return p;
  };
  float*  H      = (float*)alloc((size_t)NP * CO * 4);
  float*  psum   = (float*)alloc(64 * CO * 4);
  float*  psq    = (float*)alloc(64 * CO * 4);
  float*  scale  = (float*)alloc(CO * 4);
  float*  shift  = (float*)alloc(CO * 4);
  int*    flags  = (int*)  alloc(NP * 4);
  int*    sel    = (int*)  alloc(MS * 4);
  int*    count  = (int*)  alloc(NP * 4);
  int*    offs   = (int*)  alloc((NP + 1) * 4);
  int*    cursor = (int*)  alloc(NP * 4);
  int*    esrc   = (int*)  alloc(NE * 4);
  int*    cid    = (int*)  alloc(NP * 4);
  int*    cnt    = (int*)  alloc(NCELL * 4);
  int*    ccur   = (int*)  alloc(NCELL * 4);
  float4* spos   = (float4*)alloc((size_t)NP * 16);
  (void)ws_size;

  hipMemsetAsync(flags, 0, NP * 4, stream);
  hipMemsetAsync(count, 0, NP * 4, stream);
  hipMemsetAsync(cnt,   0, NCELL * 4, stream);

  // spatial sort for FPS pruning
  cell_kernel<<<NP / 256, 256, 0, stream>>>(pos, cid, cnt);
  cellscan_kernel<<<1, 1024, 0, stream>>>(cnt, ccur);
  cellscatter_kernel<<<NP / 256, 256, 0, stream>>>(pos, cid, ccur, spos);
  // FPS
  fps_kernel<<<1, 1024, 0, stream>>>(spos, pos, flags);
  compact_kernel<<<1, 1024, 0, stream>>>(flags, sel);
  // Linear + BN + ReLU
  gemm_kernel<<<dim3(NP / 64, CO / 64), 256, 0, stream>>>(x, W, bias, H);
  bn_stats_kernel<<<dim3(2, 64), 256, 0, stream>>>(H, psum, psq);
  bn_final_kernel<<<1, 512, 0, stream>>>(psum, psq, gamma, beta, scale, shift);
  bn_relu_kernel<<<2048, 256, 0, stream>>>(H, scale, shift);
  // edge CSR by dst
  edge_count_kernel<<<512, 256, 0, stream>>>(edge, count);
  scan_offsets_kernel<<<1, 1024, 0, stream>>>(count, offs, cursor);
  edge_scatter_kernel<<<512, 256, 0, stream>>>(edge, cursor, esrc);
  // pooled features + pos/batch gather
  pool_kernel<<<MS, 256, 0, stream>>>(H, sel, offs, esrc, out);
  gather_pb_kernel<<<MS / 256, 256, 0, stream>>>(pos, batch, sel, out);
}

// Round 8
// 13656.529 us; speedup vs baseline: 3.2736x; 1.0047x over previous
//
#include <hip/hip_runtime.h>
#include <hip/hip_bf16.h>
#include <math.h>

#define NP 16384
#define CI 512
#define CO 512
#define NE 262144
#define MS 8192
#define BN_EPS 1e-5f
#define NCELL 4096

// ---------------------------------------------------------------------------
// GEMM: H[n][o] = sum_k X[n][k]*W[o][k] + b[o]
// ---------------------------------------------------------------------------
__global__ __launch_bounds__(256) void gemm_kernel(const float* __restrict__ X,
                                                   const float* __restrict__ W,
                                                   const float* __restrict__ bias,
                                                   float* __restrict__ H) {
  __shared__ float As[16][65];
  __shared__ float Bs[16][65];
  const int bm = blockIdx.x * 64;
  const int bn = blockIdx.y * 64;
  const int t  = threadIdx.x;
  const int tm = (t >> 4) << 2;
  const int tn = (t & 15) << 2;
  const int lr = t >> 2;
  const int lc = (t & 3) << 2;

  float acc[4][4] = {};

  for (int k0 = 0; k0 < CI; k0 += 16) {
    float4 a = *(const float4*)(X + (size_t)(bm + lr) * CI + k0 + lc);
    float4 b = *(const float4*)(W + (size_t)(bn + lr) * CI + k0 + lc);
    As[lc + 0][lr] = a.x; As[lc + 1][lr] = a.y; As[lc + 2][lr] = a.z; As[lc + 3][lr] = a.w;
    Bs[lc + 0][lr] = b.x; Bs[lc + 1][lr] = b.y; Bs[lc + 2][lr] = b.z; Bs[lc + 3][lr] = b.w;
    __syncthreads();
#pragma unroll
    for (int k = 0; k < 16; ++k) {
      float av[4], bv[4];
#pragma unroll
      for (int i = 0; i < 4; ++i) av[i] = As[k][tm + i];
#pragma unroll
      for (int j = 0; j < 4; ++j) bv[j] = Bs[k][tn + j];
#pragma unroll
      for (int i = 0; i < 4; ++i)
#pragma unroll
        for (int j = 0; j < 4; ++j) acc[i][j] += av[i] * bv[j];
    }
    __syncthreads();
  }
#pragma unroll
  for (int i = 0; i < 4; ++i)
#pragma unroll
    for (int j = 0; j < 4; ++j)
      H[(size_t)(bm + tm + i) * CO + bn + tn + j] = acc[i][j] + bias[bn + tn + j];
}

// ---------------------------------------------------------------------------
// BN
// ---------------------------------------------------------------------------
__global__ __launch_bounds__(256) void bn_stats_kernel(const float* __restrict__ H,
                                                       float* __restrict__ psum,
                                                       float* __restrict__ psq) {
  const int col = blockIdx.x * 256 + threadIdx.x;
  const int r0  = blockIdx.y * 256;
  float s = 0.f, q = 0.f;
  for (int r = r0; r < r0 + 256; ++r) {
    float v = H[(size_t)r * CO + col];
    s += v;
    q += v * v;
  }
  psum[blockIdx.y * CO + col] = s;
  psq [blockIdx.y * CO + col] = q;
}

__global__ __launch_bounds__(512) void bn_final_kernel(const float* __restrict__ psum,
                                                       const float* __restrict__ psq,
                                                       const float* __restrict__ gamma,
                                                       const float* __restrict__ beta,
                                                       float* __restrict__ scale,
                                                       float* __restrict__ shift) {
  const int c = threadIdx.x;
  float s = 0.f, q = 0.f;
  for (int r = 0; r < 64; ++r) {
    s += psum[r * CO + c];
    q += psq [r * CO + c];
  }
  const float inv_n = 1.0f / (float)NP;
  float mu  = s * inv_n;
  float var = q * inv_n - mu * mu;
  float rs  = rsqrtf(var + BN_EPS);
  float a   = rs * gamma[c];
  scale[c] = a;
  shift[c] = beta[c] - mu * a;
}

__global__ __launch_bounds__(256) void bn_relu_kernel(float* __restrict__ H,
                                                      const float* __restrict__ scale,
                                                      const float* __restrict__ shift) {
  __shared__ float sc[CO], sh[CO];
  for (int i = threadIdx.x; i < CO; i += 256) { sc[i] = scale[i]; sh[i] = shift[i]; }
  __syncthreads();
  const int total4 = NP * CO / 4;
  const int stride = gridDim.x * blockDim.x;
  for (int idx = blockIdx.x * blockDim.x + threadIdx.x; idx < total4; idx += stride) {
    float4 v = ((float4*)H)[idx];
    int c = (idx << 2) & (CO - 1);
    v.x = fmaxf(fmaf(v.x, sc[c + 0], sh[c + 0]), 0.f);
    v.y = fmaxf(fmaf(v.y, sc[c + 1], sh[c + 1]), 0.f);
    v.z = fmaxf(fmaf(v.z, sc[c + 2], sh[c + 2]), 0.f);
    v.w = fmaxf(fmaf(v.w, sc[c + 3], sh[c + 3]), 0.f);
    ((float4*)H)[idx] = v;
  }
}

// ---------------------------------------------------------------------------
// Morton-cell counting sort
// ---------------------------------------------------------------------------
__device__ __forceinline__ unsigned p3(unsigned v) {
  v &= 0x3FFu;
  v = (v * 0x00010001u) & 0xFF0000FFu;
  v = (v * 0x00000101u) & 0x0F00F00Fu;
  v = (v * 0x00000011u) & 0xC30C30C3u;
  v = (v * 0x00000005u) & 0x49249249u;
  return v;
}

__global__ __launch_bounds__(256) void cell_kernel(const float* __restrict__ pos,
                                                   int* __restrict__ cid,
                                                   int* __restrict__ cnt) {
  int i = blockIdx.x * 256 + threadIdx.x;
  if (i < NP) {
    int cx = min(15, max(0, (int)(pos[3 * i + 0] * 16.f)));
    int cy = min(15, max(0, (int)(pos[3 * i + 1] * 16.f)));
    int cz = min(15, max(0, (int)(pos[3 * i + 2] * 16.f)));
    int c = (int)(p3(cx) | (p3(cy) << 1) | (p3(cz) << 2));
    cid[i] = c;
    atomicAdd(&cnt[c], 1);
  }
}

__global__ __launch_bounds__(1024) void cellscan_kernel(const int* __restrict__ cnt,
                                                        int* __restrict__ ccur) {
  const int t = threadIdx.x;
  const int base = t * 4;
  int c[4];
  int s = 0;
#pragma unroll
  for (int j = 0; j < 4; ++j) { c[j] = cnt[base + j]; s += c[j]; }
  const int lane = t & 63, wid = t >> 6;
  int incl = s;
#pragma unroll
  for (int off = 1; off < 64; off <<= 1) {
    int v = __shfl_up(incl, off);
    if (lane >= off) incl += v;
  }
  __shared__ int wtot[16];
  if (lane == 63) wtot[wid] = incl;
  __syncthreads();
  if (t < 16) {
    int v = wtot[t];
    int p = v;
#pragma unroll
    for (int off = 1; off < 16; off <<= 1) {
      int u = __shfl_up(p, off);
      if (t >= off) p += u;
    }
    wtot[t] = p - v;
  }
  __syncthreads();
  int off = wtot[wid] + incl - s;
#pragma unroll
  for (int j = 0; j < 4; ++j) { ccur[base + j] = off; off += c[j]; }
}

__global__ __launch_bounds__(256) void cellscatter_kernel(const float* __restrict__ pos,
                                                          const int* __restrict__ cid,
                                                          int* __restrict__ ccur,
                                                          float4* __restrict__ spos) {
  int i = blockIdx.x * 256 + threadIdx.x;
  if (i < NP) {
    int p = atomicAdd(&ccur[cid[i]], 1);
    spos[p] = make_float4(pos[3 * i + 0], pos[3 * i + 1], pos[3 * i + 2],
                          __int_as_float(i));
  }
}

// ---------------------------------------------------------------------------
// FPS: 1024 threads (16 waves), 16 points/lane TRULY register-resident:
// __launch_bounds__(1024, 4) raises the VGPR cap to 128 (16 waves/CU),
// fitting 64 floats of state + working set with no scratch spill.
// Wave-level prune: wave recomputes ALL its lanes iff any lane's group might
// change (straight-line body, no per-lane divergence; fmin idempotent+margin
// => bit-exact). Idle waves replay a cached slot. One barrier/iteration.
// dmin update keeps the exact XLA rounding chain; tie-breaks everywhere
// resolve to the first (lowest-index) max.
// ---------------------------------------------------------------------------
template <int CTRL>
__device__ __forceinline__ float dpp_max_step(float v) {
  int o = __builtin_amdgcn_update_dpp(__float_as_int(v), __float_as_int(v),
                                      CTRL, 0xf, 0xf, false);
  return fmaxf(v, __int_as_float(o));
}
__device__ __forceinline__ float readlane_f(float v, int lane) {
  return __int_as_float(__builtin_amdgcn_readlane(__float_as_int(v), lane));
}

__global__ __launch_bounds__(1024, 4) void fps_kernel(const float4* __restrict__ spos,
                                                      const float* __restrict__ pos,
                                                      int* __restrict__ flags) {
  const int t = threadIdx.x;
  const int lane = t & 63;
  const int w = t >> 6;      // 0..15

  __shared__ int    sorig[NP];     // sorted -> original index (64 KB)
  __shared__ float4 slotA[2][16];  // (val, x, y, z)
  __shared__ int    slotB[2][16];  // winner sorted index

  float px[16], py[16], pz[16], dmin[16];
  const float4* sp = spos + (size_t)t * 16;
#pragma unroll
  for (int k = 0; k < 16; ++k) {
    float4 p = sp[k];
    px[k] = p.x; py[k] = p.y; pz[k] = p.z;
    dmin[k] = __builtin_huge_valf();
    sorig[t * 16 + k] = __float_as_int(p.w);
  }

  // group geometry: center + inflated radius (one group of 16 per lane)
  float lox = px[0], hix = lox, loy = py[0], hiy = loy, loz = pz[0], hiz = loz;
#pragma unroll
  for (int j = 1; j < 16; ++j) {
    lox = fminf(lox, px[j]); hix = fmaxf(hix, px[j]);
    loy = fminf(loy, py[j]); hiy = fmaxf(hiy, py[j]);
    loz = fminf(loz, pz[j]); hiz = fmaxf(hiz, pz[j]);
  }
  const float cgx = 0.5f * (lox + hix), cgy = 0.5f * (loy + hiy), cgz = 0.5f * (loz + hiz);
  float r2 = 0.f;
#pragma unroll
  for (int j = 0; j < 16; ++j) {
    float dx = px[j] - cgx, dy = py[j] - cgy, dz = pz[j] - cgz;
    r2 = fmaxf(r2, dx * dx + dy * dy + dz * dz);
  }
  const float rad = sqrtf(r2) * 1.0001f + 1e-7f;
  float ssq = __builtin_huge_valf();   // inflated sqrt of this lane's group max

  // cached wave-winner slot payload (wave-uniform once written)
  float cwv = -1.f, cwx = 0.f, cwy = 0.f, cwz = 0.f;
  int   cwi = 0;

  float ccx = pos[0], ccy = pos[1], ccz = pos[2];
  if (t == 0) flags[0] = 1;
  __syncthreads();

  for (int it = 1; it < MS; ++it) {
    float dxc = ccx - cgx, dyc = ccy - cgy, dzc = ccz - cgz;
    float d2c = fmaf(dxc, dxc, fmaf(dyc, dyc, dzc * dzc));
    float thr = ssq + rad;
    bool hit = d2c < thr * thr;
    if (__any(hit)) {   // wave-uniform: active wave recomputes ALL lanes
      float bv = -1.f, bx = 0.f, by = 0.f, bz = 0.f;
      int bk = 0;
#pragma unroll
      for (int k = 0; k < 16; ++k) {
        float dx = __fsub_rn(px[k], ccx);
        float dy = __fsub_rn(py[k], ccy);
        float dz = __fsub_rn(pz[k], ccz);
        float d  = __fadd_rn(__fadd_rn(__fmul_rn(dx, dx), __fmul_rn(dy, dy)),
                             __fmul_rn(dz, dz));
        float dm = fminf(dmin[k], d);
        dmin[k] = dm;
        if (dm > bv) { bv = dm; bk = k; bx = px[k]; by = py[k]; bz = pz[k]; }
      }
      ssq = sqrtf(bv) * 1.0001f;
      // wave argmax: DPP value max -> lane 63, ballot + readlane extraction
      float m = bv;
      m = dpp_max_step<0x111>(m);  // row_shr:1
      m = dpp_max_step<0x112>(m);  // row_shr:2
      m = dpp_max_step<0x114>(m);  // row_shr:4
      m = dpp_max_step<0x118>(m);  // row_shr:8
      m = dpp_max_step<0x142>(m);  // row_bcast:15
      m = dpp_max_step<0x143>(m);  // row_bcast:31
      float wmax = readlane_f(m, 63);
      unsigned long long ball = __ballot(bv == wmax);
      int srcl = (int)__ffsll(ball) - 1;   // lowest lane = lowest sorted idx
      int gi = t * 16 + bk;
      cwi = __builtin_amdgcn_readlane(gi, srcl);
      cwx = readlane_f(bx, srcl);
      cwy = readlane_f(by, srcl);
      cwz = readlane_f(bz, srcl);
      cwv = wmax;
    }
    const int b = it & 1;
    if (lane == 0) {
      slotA[b][w] = make_float4(cwv, cwx, cwy, cwz);
      slotB[b][w] = cwi;
    }
    __syncthreads();

    // exchange: lane reads slot (lane&15); 4-step shfl_xor reduce on (v,slot)
    const int q = lane & 15;
    float4 sa = slotA[b][q];
    int    sb = slotB[b][q];
    float v2 = sa.x;
    int   qi = q;
#pragma unroll
    for (int off = 1; off < 16; off <<= 1) {
      float ov = __shfl_xor(v2, off);
      int   oq = __shfl_xor(qi, off);
      if (ov > v2 || (ov == v2 && oq < qi)) { v2 = ov; qi = oq; }
    }
    // winner slot qi is uniform; its payload lives in lane qi (qi < 16)
    ccx = readlane_f(sa.y, qi);
    ccy = readlane_f(sa.z, qi);
    ccz = readlane_f(sa.w, qi);
    if (t == 0) {
      int gidx = __builtin_amdgcn_readlane(sb, qi);
      flags[sorig[gidx]] = 1;
    }
  }
}

// ---------------------------------------------------------------------------
// Compact flags -> sorted selected original indices
// ---------------------------------------------------------------------------
__global__ __launch_bounds__(1024) void compact_kernel(const int* __restrict__ flags,
                                                       int* __restrict__ sel) {
  const int t = threadIdx.x;
  const int base = t * 16;
  int f[16];
  int cnt = 0;
#pragma unroll
  for (int j = 0; j < 16; ++j) { f[j] = flags[base + j]; cnt += f[j]; }
  const int lane = t & 63, wid = t >> 6;
  int incl = cnt;
#pragma unroll
  for (int off = 1; off < 64; off <<= 1) {
    int v = __shfl_up(incl, off);
    if (lane >= off) incl += v;
  }
  __shared__ int wtot[16];
  if (lane == 63) wtot[wid] = incl;
  __syncthreads();
  if (t < 16) {
    int v = wtot[t];
    int s = v;
#pragma unroll
    for (int off = 1; off < 16; off <<= 1) {
      int u = __shfl_up(s, off);
      if (t >= off) s += u;
    }
    wtot[t] = s - v;
  }
  __syncthreads();
  int off = wtot[wid] + incl - cnt;
#pragma unroll
  for (int j = 0; j < 16; ++j)
    if (f[j]) sel[off++] = base + j;
}

// ---------------------------------------------------------------------------
// Edge CSR by dst
// ---------------------------------------------------------------------------
__global__ __launch_bounds__(256) void edge_count_kernel(const int* __restrict__ edge,
                                                         int* __restrict__ count) {
  const int stride = gridDim.x * blockDim.x;
  for (int e = blockIdx.x * blockDim.x + threadIdx.x; e < NE; e += stride)
    atomicAdd(&count[edge[NE + e]], 1);
}

__global__ __launch_bounds__(1024) void scan_offsets_kernel(const int* __restrict__ count,
                                                            int* __restrict__ offs,
                                                            int* __restrict__ cursor) {
  const int t = threadIdx.x;
  const int base = t * 16;
  int c[16];
  int cnt = 0;
#pragma unroll
  for (int j = 0; j < 16; ++j) { c[j] = count[base + j]; cnt += c[j]; }
  const int lane = t & 63, wid = t >> 6;
  int incl = cnt;
#pragma unroll
  for (int off = 1; off < 64; off <<= 1) {
    int v = __shfl_up(incl, off);
    if (lane >= off) incl += v;
  }
  __shared__ int wtot[16];
  if (lane == 63) wtot[wid] = incl;
  __syncthreads();
  if (t < 16) {
    int v = wtot[t];
    int s = v;
#pragma unroll
    for (int off = 1; off < 16; off <<= 1) {
      int u = __shfl_up(s, off);
      if (t >= off) s += u;
    }
    wtot[t] = s - v;
  }
  __syncthreads();
  int off = wtot[wid] + incl - cnt;
#pragma unroll
  for (int j = 0; j < 16; ++j) {
    offs[base + j] = off;
    cursor[base + j] = off;
    off += c[j];
  }
  if (t == 1023) offs[NP] = off;
}

__global__ __launch_bounds__(256) void edge_scatter_kernel(const int* __restrict__ edge,
                                                           int* __restrict__ cursor,
                                                           int* __restrict__ esrc) {
  const int stride = gridDim.x * blockDim.x;
  for (int e = blockIdx.x * blockDim.x + threadIdx.x; e < NE; e += stride) {
    int p = atomicAdd(&cursor[edge[NE + e]], 1);
    esrc[p] = edge[e];
  }
}

// ---------------------------------------------------------------------------
// Pool + gather
// ---------------------------------------------------------------------------
__global__ __launch_bounds__(256) void pool_kernel(const float* __restrict__ H,
                                                   const int* __restrict__ sel,
                                                   const int* __restrict__ offs,
                                                   const int* __restrict__ esrc,
                                                   float* __restrict__ out) {
  const int m = blockIdx.x;
  const int i = sel[m];
  const int c = threadIdx.x;
  float v0 = H[(size_t)i * CO + c];
  float v1 = H[(size_t)i * CO + c + 256];
  const int s0 = offs[i], s1 = offs[i + 1];
  for (int k = s0; k < s1; ++k) {
    const int s = esrc[k];
    v0 = fmaxf(v0, H[(size_t)s * CO + c]);
    v1 = fmaxf(v1, H[(size_t)s * CO + c + 256]);
  }
  out[(size_t)m * CO + c] = v0;
  out[(size_t)m * CO + c + 256] = v1;
}

__global__ __launch_bounds__(256) void gather_pb_kernel(const float* __restrict__ pos,
                                                        const int* __restrict__ batch,
                                                        const int* __restrict__ sel,
                                                        float* __restrict__ out) {
  const int m = blockIdx.x * blockDim.x + threadIdx.x;
  if (m < MS) {
    const int i = sel[m];
    float* opos = out + (size_t)MS * CO;
    opos[3 * m + 0] = pos[3 * i + 0];
    opos[3 * m + 1] = pos[3 * i + 1];
    opos[3 * m + 2] = pos[3 * i + 2];
    ((int*)out)[(size_t)MS * CO + MS * 3 + m] = batch[i];
  }
}

// ---------------------------------------------------------------------------
extern "C" void kernel_launch(void* const* d_in, const int* in_sizes, int n_in,
                              void* d_out, int out_size, void* d_ws, size_t ws_size,
                              hipStream_t stream) {
  const float* x     = (const float*)d_in[0];
  const float* pos   = (const float*)d_in[1];
  const int*   batch = (const int*)  d_in[2];
  const int*   edge  = (const int*)  d_in[3];
  const float* W     = (const float*)d_in[4];
  const float* bias  = (const float*)d_in[5];
  const float* gamma = (const float*)d_in[6];
  const float* beta  = (const float*)d_in[7];
  float* out = (float*)d_out;

  char* ws = (char*)d_ws;
  size_t off = 0;
  auto alloc = [&](size_t bytes) -> void* {
    void* p = ws + off;
    off += (bytes + 255) & ~(size_t)255;
    return p;
  };
  float*  H      = (float*)alloc((size_t)NP * CO * 4);
  float*  psum   = (float*)alloc(64 * CO * 4);
  float*  psq    = (float*)alloc(64 * CO * 4);
  float*  scale  = (float*)alloc(CO * 4);
  float*  shift  = (float*)alloc(CO * 4);
  int*    flags  = (int*)  alloc(NP * 4);
  int*    sel    = (int*)  alloc(MS * 4);
  int*    count  = (int*)  alloc(NP * 4);
  int*    offs   = (int*)  alloc((NP + 1) * 4);
  int*    cursor = (int*)  alloc(NP * 4);
  int*    esrc   = (int*)  alloc(NE * 4);
  int*    cid    = (int*)  alloc(NP * 4);
  int*    cnt    = (int*)  alloc(NCELL * 4);
  int*    ccur   = (int*)  alloc(NCELL * 4);
  float4* spos   = (float4*)alloc((size_t)NP * 16);
  (void)ws_size;

  hipMemsetAsync(flags, 0, NP * 4, stream);
  hipMemsetAsync(count, 0, NP * 4, stream);
  hipMemsetAsync(cnt,   0, NCELL * 4, stream);

  // spatial sort for FPS pruning
  cell_kernel<<<NP / 256, 256, 0, stream>>>(pos, cid, cnt);
  cellscan_kernel<<<1, 1024, 0, stream>>>(cnt, ccur);
  cellscatter_kernel<<<NP / 256, 256, 0, stream>>>(pos, cid, ccur, spos);
  // FPS
  fps_kernel<<<1, 1024, 0, stream>>>(spos, pos, flags);
  compact_kernel<<<1, 1024, 0, stream>>>(flags, sel);
  // Linear + BN + ReLU
  gemm_kernel<<<dim3(NP / 64, CO / 64), 256, 0, stream>>>(x, W, bias, H);
  bn_stats_kernel<<<dim3(2, 64), 256, 0, stream>>>(H, psum, psq);
  bn_final_kernel<<<1, 512, 0, stream>>>(psum, psq, gamma, beta, scale, shift);
  bn_relu_kernel<<<2048, 256, 0, stream>>>(H, scale, shift);
  // edge CSR by dst
  edge_count_kernel<<<512, 256, 0, stream>>>(edge, count);
  scan_offsets_kernel<<<1, 1024, 0, stream>>>(count, offs, cursor);
  edge_scatter_kernel<<<512, 256, 0, stream>>>(edge, cursor, esrc);
  // pooled features + pos/batch gather
  pool_kernel<<<MS, 256, 0, stream>>>(H, sel, offs, esrc, out);
  gather_pb_kernel<<<MS / 256, 256, 0, stream>>>(pos, batch, sel, out);
}